// Round 2
// baseline (1483.197 us; speedup 1.0000x reference)
//
#include <hip/hip_runtime.h>
#include <hip/hip_bf16.h>
#include <math.h>

#define NUM_EXPERTS 32
#define TOP_K 8
#define HIDDEN 1536
#define INTER 512

typedef __bf16 bf16_t;
typedef __bf16 bf16x8 __attribute__((ext_vector_type(8)));
typedef __bf16 bf16x4 __attribute__((ext_vector_type(4)));
typedef float f32x4 __attribute__((ext_vector_type(4)));

// meta layout (int indices)
#define M_COUNTS    0     // 32
#define M_OFFSETS   32    // 33
#define M_CURSORS   96    // 32
#define M_NUMTILES  128   // 1
#define M_TILE_E    256   // up to 640
#define M_TILE_M0   1024  // up to 640
#define M_TILE_ROWS 2048  // up to 640
#define META_BYTES  16384

__device__ __forceinline__ void gld16(void* lds, const void* gsrc) {
  __builtin_amdgcn_global_load_lds(
      (const __attribute__((address_space(1))) void*)gsrc,
      (__attribute__((address_space(3))) void*)lds, 16, 0, 0);
}

// ---------------- fp32 -> bf16 bulk convert ----------------
__global__ __launch_bounds__(256) void k_cvt(
    const float* __restrict__ src, bf16_t* __restrict__ dst)
{
  size_t i = ((size_t)blockIdx.x * 256 + threadIdx.x) * 4;
  f32x4 v = *(const f32x4*)(src + i);
  bf16x4 o;
  o[0] = (bf16_t)v[0]; o[1] = (bf16_t)v[1]; o[2] = (bf16_t)v[2]; o[3] = (bf16_t)v[3];
  *(bf16x4*)(dst + i) = o;
}

// ---------------- router: fp32 logits -> top8 -> weights + counts ----------------
__global__ __launch_bounds__(64) void k_router(
    const float* __restrict__ x, const float* __restrict__ gw,
    int* __restrict__ meta, int* __restrict__ topk_idx, float* __restrict__ topk_w)
{
  int t = blockIdx.x;
  int lane = threadIdx.x;          // 64 lanes
  int e = lane & 31, part = lane >> 5;
  const f32x4* xr = (const f32x4*)(x + (size_t)t * HIDDEN + part * 768);
  const f32x4* gr = (const f32x4*)(gw + (size_t)e * HIDDEN + part * 768);
  float s = 0.f;
#pragma unroll 4
  for (int i = 0; i < 192; ++i) {
    f32x4 xv = xr[i], gv = gr[i];
    s += xv[0] * gv[0] + xv[1] * gv[1] + xv[2] * gv[2] + xv[3] * gv[3];
  }
  s += __shfl_xor(s, 32);          // full dot; lanes 0..31 (and dup 32..63) hold logit[e]
  float logit = s, rem = s;
  float m0 = 0.f, wsum = 0.f, my_l = 0.f;
  int my_e = 0;
#pragma unroll
  for (int k = 0; k < TOP_K; ++k) {
    float mx = rem;
#pragma unroll
    for (int off = 32; off >= 1; off >>= 1) mx = fmaxf(mx, __shfl_xor(mx, off));
    unsigned long long bal = __ballot(rem == mx);
    int src = __ffsll(bal) - 1;    // lowest lane -> lowest expert idx on ties
    int ex = src & 31;
    float lv = __shfl(logit, ex);
    if (k == 0) m0 = mx;
    wsum += __expf(lv - m0);
    if (lane == k) { my_e = ex; my_l = lv; }
    if ((lane & 31) == ex) rem = -1e30f;
  }
  if (lane < TOP_K) {
    topk_idx[t * TOP_K + lane] = my_e;
    topk_w[t * TOP_K + lane] = __expf(my_l - m0) / wsum;
    atomicAdd(&meta[M_COUNTS + my_e], 1);
  }
}

// ---------------- prefix sum + tile descriptors (tiny, 1 thread) ----------------
__global__ void k_scan(int* __restrict__ meta)
{
  if (threadIdx.x != 0 || blockIdx.x != 0) return;
  int off = 0, nt = 0;
  for (int e = 0; e < NUM_EXPERTS; ++e) {
    int n = meta[M_COUNTS + e];
    meta[M_OFFSETS + e] = off;
    meta[M_CURSORS + e] = off;
    int tn = (n + 127) >> 7;
    for (int i = 0; i < tn; ++i) {
      meta[M_TILE_E + nt] = e;
      meta[M_TILE_M0 + nt] = off + i * 128;
      meta[M_TILE_ROWS + nt] = min(128, n - i * 128);
      ++nt;
    }
    off += n;
  }
  meta[M_OFFSETS + NUM_EXPERTS] = off;
  meta[M_NUMTILES] = nt;
}

// ---------------- scatter pairs into expert-sorted order ----------------
__global__ __launch_bounds__(256) void k_scatter(
    const int* __restrict__ topk_idx, const float* __restrict__ topk_w,
    int* __restrict__ meta, int* __restrict__ pair_token, float* __restrict__ pair_weight)
{
  int i = blockIdx.x * 256 + threadIdx.x;   // 0..T*8-1
  int e = topk_idx[i];
  int pos = atomicAdd(&meta[M_CURSORS + e], 1);
  pair_token[pos] = i >> 3;
  pair_weight[pos] = topk_w[i];
}

// ---------------- GEMM1: act = silu(x@Wg^T) * (x@Wu^T), gathered rows ----------------
// Block: 256 thr (4 waves): wave w owns tile rows w*32..w*32+31, all 128 cols.
// C tile: 128 pair-rows x 128 cols; cols 0..63 = g cols [n0g,n0g+64),
//         cols 64..127 = u cols (w13 rows 512+n0g+..)  -> silu fuse is per-lane.
// LDS tiles [128][64] bf16, 16B-chunk XOR swizzle: LDS[r][c] = src row r chunk c^(r&7).
__global__ __launch_bounds__(256, 2) void k_gemm1(
    const bf16_t* __restrict__ x, const bf16_t* __restrict__ w13,
    const int* __restrict__ meta, const int* __restrict__ pair_token,
    bf16_t* __restrict__ act)
{
  int tile = blockIdx.x;
  if (tile >= meta[M_NUMTILES]) return;
  int e    = meta[M_TILE_E + tile];
  int m0   = meta[M_TILE_M0 + tile];
  int rows = meta[M_TILE_ROWS + tile];
  int n0g  = blockIdx.y * 64;

  __shared__ __align__(16) char smem[32768];
  char* As = smem;           // [128][64] bf16 swizzled
  char* Bs = smem + 16384;

  int tid = threadIdx.x;
  int lane = tid & 63, w = tid >> 6;
  int cd = lane & 7;                 // LDS chunk this lane deposits (dest = base + lane*16)
  int lrow = w * 8 + (lane >> 3);    // + i*32 -> row 0..127

  const bf16_t* a_src[4];
  const bf16_t* b_src[4];
#pragma unroll
  for (int i = 0; i < 4; ++i) {
    int r = i * 32 + lrow;
    int rr = (r < rows) ? r : 0;               // clamp ragged rows to a valid token
    int tok = pair_token[m0 + rr];
    int cg = cd ^ (r & 7);                     // source chunk for swizzled store
    a_src[i] = x + (size_t)tok * HIDDEN + cg * 8;
    int gr = (r < 64) ? (n0g + r) : (512 + n0g + (r - 64));
    b_src[i] = w13 + (size_t)e * (2 * INTER) * HIDDEN + (size_t)gr * HIDDEN + cg * 8;
  }
  unsigned lds_off = w * 1024 + lane * 16;     // wave-contiguous (global_load_lds semantics)

  f32x4 acc[2][8] = {};
  int q = lane >> 4, cl = lane & 15;
  int arow0 = (w * 32 + cl) * 128;
  int arow1 = (w * 32 + 16 + cl) * 128;

  for (int k0 = 0; k0 < HIDDEN; k0 += 64) {
#pragma unroll
    for (int i = 0; i < 4; ++i) gld16(As + i * 4096 + lds_off, a_src[i] + k0);
#pragma unroll
    for (int i = 0; i < 4; ++i) gld16(Bs + i * 4096 + lds_off, b_src[i] + k0);
    __syncthreads();
#pragma unroll
    for (int ks = 0; ks < 2; ++ks) {
      int csw = ((ks * 4 + q) ^ (lane & 7)) * 16;   // un-swizzle: frag rows have row&7 == lane&7
      bf16x8 a0 = *(const bf16x8*)(As + arow0 + csw);
      bf16x8 a1 = *(const bf16x8*)(As + arow1 + csw);
#pragma unroll
      for (int in = 0; in < 8; ++in) {
        bf16x8 b = *(const bf16x8*)(Bs + (in * 16 + cl) * 128 + csw);
        acc[0][in] = __builtin_amdgcn_mfma_f32_16x16x32_bf16(a0, b, acc[0][in], 0, 0, 0);
        acc[1][in] = __builtin_amdgcn_mfma_f32_16x16x32_bf16(a1, b, acc[1][in], 0, 0, 0);
      }
    }
    __syncthreads();
  }

  // epilogue: act = silu(g)*u ; g = acc[.][0..3], u = acc[.][4..7] -> same lane, per-lane math
#pragma unroll
  for (int im = 0; im < 2; ++im) {
#pragma unroll
    for (int reg = 0; reg < 4; ++reg) {
      int row = w * 32 + im * 16 + q * 4 + reg;   // C/D: row=(lane>>4)*4+reg, col=lane&15
      if (row < rows) {
        bf16_t* obase = act + (size_t)(m0 + row) * INTER + n0g + cl;
#pragma unroll
        for (int in = 0; in < 4; ++in) {
          float g = acc[im][in][reg];
          float u = acc[im][in + 4][reg];
          float a = (g / (1.f + __expf(-g))) * u;
          obase[in * 16] = (bf16_t)a;
        }
      }
    }
  }
}

// ---------------- GEMM2: out += pw * (act @ w2^T), atomic fp32 accumulate ----------------
__global__ __launch_bounds__(256, 2) void k_gemm2(
    const bf16_t* __restrict__ act, const bf16_t* __restrict__ w2,
    const int* __restrict__ meta, const int* __restrict__ pair_token,
    const float* __restrict__ pair_weight, float* __restrict__ out)
{
  int tile = blockIdx.x;
  if (tile >= meta[M_NUMTILES]) return;
  int e    = meta[M_TILE_E + tile];
  int m0   = meta[M_TILE_M0 + tile];
  int rows = meta[M_TILE_ROWS + tile];
  int n0   = blockIdx.y * 128;

  __shared__ __align__(16) char smem[32768];
  char* As = smem;
  char* Bs = smem + 16384;

  int tid = threadIdx.x;
  int lane = tid & 63, w = tid >> 6;
  int cd = lane & 7;
  int lrow = w * 8 + (lane >> 3);

  const bf16_t* a_src[4];
  const bf16_t* b_src[4];
#pragma unroll
  for (int i = 0; i < 4; ++i) {
    int r = i * 32 + lrow;
    int rr = (r < rows) ? r : 0;
    int cg = cd ^ (r & 7);
    a_src[i] = act + (size_t)(m0 + rr) * INTER + cg * 8;
    b_src[i] = w2 + (size_t)e * HIDDEN * INTER + (size_t)(n0 + r) * INTER + cg * 8;
  }
  unsigned lds_off = w * 1024 + lane * 16;

  f32x4 acc[2][8] = {};
  int q = lane >> 4, cl = lane & 15;
  int arow0 = (w * 32 + cl) * 128;
  int arow1 = (w * 32 + 16 + cl) * 128;

  for (int k0 = 0; k0 < INTER; k0 += 64) {
#pragma unroll
    for (int i = 0; i < 4; ++i) gld16(As + i * 4096 + lds_off, a_src[i] + k0);
#pragma unroll
    for (int i = 0; i < 4; ++i) gld16(Bs + i * 4096 + lds_off, b_src[i] + k0);
    __syncthreads();
#pragma unroll
    for (int ks = 0; ks < 2; ++ks) {
      int csw = ((ks * 4 + q) ^ (lane & 7)) * 16;
      bf16x8 a0 = *(const bf16x8*)(As + arow0 + csw);
      bf16x8 a1 = *(const bf16x8*)(As + arow1 + csw);
#pragma unroll
      for (int in = 0; in < 8; ++in) {
        bf16x8 b = *(const bf16x8*)(Bs + (in * 16 + cl) * 128 + csw);
        acc[0][in] = __builtin_amdgcn_mfma_f32_16x16x32_bf16(a0, b, acc[0][in], 0, 0, 0);
        acc[1][in] = __builtin_amdgcn_mfma_f32_16x16x32_bf16(a1, b, acc[1][in], 0, 0, 0);
      }
    }
    __syncthreads();
  }

#pragma unroll
  for (int im = 0; im < 2; ++im) {
#pragma unroll
    for (int reg = 0; reg < 4; ++reg) {
      int row = w * 32 + im * 16 + q * 4 + reg;
      if (row < rows) {
        int p = m0 + row;
        int tok = pair_token[p];
        float pw = pair_weight[p];
        float* obase = out + (size_t)tok * HIDDEN + n0 + cl;
#pragma unroll
        for (int in = 0; in < 8; ++in)
          unsafeAtomicAdd(obase + in * 16, acc[im][in][reg] * pw);
      }
    }
  }
}

extern "C" void kernel_launch(void* const* d_in, const int* in_sizes, int n_in,
                              void* d_out, int out_size, void* d_ws, size_t ws_size,
                              hipStream_t stream)
{
  const float* x   = (const float*)d_in[0];
  const float* gw  = (const float*)d_in[1];
  const float* w13 = (const float*)d_in[2];
  const float* w2  = (const float*)d_in[3];
  float* out = (float*)d_out;

  const int T = in_sizes[0] / HIDDEN;   // 8192
  const int P = T * TOP_K;              // 65536
  const size_t NX   = (size_t)T * HIDDEN;                 // 12.58M
  const size_t NW13 = (size_t)NUM_EXPERTS * 2 * INTER * HIDDEN;  // 50.33M
  const size_t NW2  = (size_t)NUM_EXPERTS * HIDDEN * INTER;      // 25.17M

  char* ws = (char*)d_ws;
  int*    meta        = (int*)ws;                              // 16 KB
  int*    topk_idx    = (int*)(ws + META_BYTES);               // P ints
  float*  topk_w      = (float*)(ws + META_BYTES + (size_t)P * 4);
  int*    pair_token  = (int*)(ws + META_BYTES + (size_t)P * 8);
  float*  pair_weight = (float*)(ws + META_BYTES + (size_t)P * 12);
  size_t off = 2u << 20;
  bf16_t* x16   = (bf16_t*)(ws + off);  off += NX * 2;         // 25.2 MB
  bf16_t* w13_16 = (bf16_t*)(ws + off); off += NW13 * 2;       // 100.7 MB
  bf16_t* w2_16  = (bf16_t*)(ws + off); off += NW2 * 2;        // 50.3 MB
  bf16_t* act    = (bf16_t*)(ws + off);                        // P*512*2 = 67.1 MB

  hipMemsetAsync(meta, 0, 32 * sizeof(int), stream);
  hipMemsetAsync(out, 0, (size_t)out_size * sizeof(float), stream);

  k_cvt<<<NX / 1024, 256, 0, stream>>>(x, x16);
  k_cvt<<<NW13 / 1024, 256, 0, stream>>>(w13, w13_16);
  k_cvt<<<NW2 / 1024, 256, 0, stream>>>(w2, w2_16);

  k_router<<<T, 64, 0, stream>>>(x, gw, meta, topk_idx, topk_w);
  k_scan<<<1, 64, 0, stream>>>(meta);
  k_scatter<<<P / 256, 256, 0, stream>>>(topk_idx, topk_w, meta, pair_token, pair_weight);

  int maxTiles = P / 128 + NUM_EXPERTS;   // 544 upper bound on ragged tiles
  k_gemm1<<<dim3(maxTiles, 8), 256, 0, stream>>>(x16, w13_16, meta, pair_token, act);
  k_gemm2<<<dim3(maxTiles, 12), 256, 0, stream>>>(act, w2_16, meta, pair_token, pair_weight, out);
}

// Round 3
// 1269.924 us; speedup vs baseline: 1.1679x; 1.1679x over previous
//
#include <hip/hip_runtime.h>
#include <hip/hip_bf16.h>
#include <math.h>

#define NUM_EXPERTS 32
#define TOP_K 8
#define HIDDEN 1536
#define INTER 512

typedef __bf16 bf16_t;
typedef __bf16 bf16x8 __attribute__((ext_vector_type(8)));
typedef __bf16 bf16x4 __attribute__((ext_vector_type(4)));
typedef float f32x4 __attribute__((ext_vector_type(4)));

// meta layout (int indices)
#define M_COUNTS    0     // 32
#define M_OFFSETS   32    // 33
#define M_CURSORS   96    // 32
#define M_NUMTILES  128   // 1
#define M_TILE_E    256   // up to 640
#define M_TILE_M0   1024  // up to 640
#define M_TILE_ROWS 2048  // up to 640
#define META_BYTES  16384

__device__ __forceinline__ void gld16(void* lds, const void* gsrc) {
  __builtin_amdgcn_global_load_lds(
      (const __attribute__((address_space(1))) void*)gsrc,
      (__attribute__((address_space(3))) void*)lds, 16, 0, 0);
}

// ---------------- fp32 -> bf16 bulk convert ----------------
__global__ __launch_bounds__(256) void k_cvt(
    const float* __restrict__ src, bf16_t* __restrict__ dst)
{
  size_t i = ((size_t)blockIdx.x * 256 + threadIdx.x) * 4;
  f32x4 v = *(const f32x4*)(src + i);
  bf16x4 o;
  o[0] = (bf16_t)v[0]; o[1] = (bf16_t)v[1]; o[2] = (bf16_t)v[2]; o[3] = (bf16_t)v[3];
  *(bf16x4*)(dst + i) = o;
}

// ---------------- gate-weight transpose: gwT4[k>>2][e][k&3] = gw[e][k] ----------------
__global__ __launch_bounds__(256) void k_tgw(
    const float* __restrict__ gw, float* __restrict__ gwT4)
{
  int tid = blockIdx.x * 256 + threadIdx.x;   // 49152
  int e = tid / HIDDEN, k = tid % HIDDEN;
  gwT4[(k >> 2) * 128 + (e << 2) + (k & 3)] = gw[tid];
}

// ---------------- router: fp32 logits -> top8 -> weights + counts; also writes x16 ----------------
__global__ __launch_bounds__(64) void k_router(
    const float* __restrict__ x, const float* __restrict__ gwT4,
    int* __restrict__ meta, int* __restrict__ topk_idx, float* __restrict__ topk_w,
    bf16_t* __restrict__ x16)
{
  int t = blockIdx.x;
  int lane = threadIdx.x;          // 64 lanes
  int e = lane & 31, part = lane >> 5;
  const float* xrow = x + (size_t)t * HIDDEN;
  const f32x4* xr = (const f32x4*)(xrow + part * 768);
  const f32x4* gr = (const f32x4*)(gwT4 + part * 192 * 128 + e * 4);
  float s = 0.f;
#pragma unroll 4
  for (int i = 0; i < 192; ++i) {
    f32x4 xv = xr[i];
    f32x4 gv = gr[i * 32];     // coalesced: lanes 0..31 read 512B contiguous
    s += xv[0] * gv[0] + xv[1] * gv[1] + xv[2] * gv[2] + xv[3] * gv[3];
  }
  s += __shfl_xor(s, 32);          // full dot; lanes 0..31 (and dup 32..63) hold logit[e]

  // fused x -> bf16 (x row is L1/L2 hot)
  {
    const f32x4* xv4 = (const f32x4*)(xrow + lane * 24);
    bf16_t* xo = x16 + (size_t)t * HIDDEN + lane * 24;
#pragma unroll
    for (int i = 0; i < 6; ++i) {
      f32x4 v = xv4[i];
      bf16x4 o;
      o[0] = (bf16_t)v[0]; o[1] = (bf16_t)v[1]; o[2] = (bf16_t)v[2]; o[3] = (bf16_t)v[3];
      *(bf16x4*)(xo + i * 4) = o;
    }
  }

  float logit = s, rem = s;
  float m0 = 0.f, wsum = 0.f, my_l = 0.f;
  int my_e = 0;
#pragma unroll
  for (int k = 0; k < TOP_K; ++k) {
    float mx = rem;
#pragma unroll
    for (int off = 32; off >= 1; off >>= 1) mx = fmaxf(mx, __shfl_xor(mx, off));
    unsigned long long bal = __ballot(rem == mx);
    int src = __ffsll(bal) - 1;    // lowest lane -> lowest expert idx on ties
    int ex = src & 31;
    float lv = __shfl(logit, ex);
    if (k == 0) m0 = mx;
    wsum += __expf(lv - m0);
    if (lane == k) { my_e = ex; my_l = lv; }
    if ((lane & 31) == ex) rem = -1e30f;
  }
  if (lane < TOP_K) {
    topk_idx[t * TOP_K + lane] = my_e;
    topk_w[t * TOP_K + lane] = __expf(my_l - m0) / wsum;
    atomicAdd(&meta[M_COUNTS + my_e], 1);
  }
}

// ---------------- prefix sum + tile descriptors (tiny, 1 thread) ----------------
__global__ void k_scan(int* __restrict__ meta)
{
  if (threadIdx.x != 0 || blockIdx.x != 0) return;
  int off = 0, nt = 0;
  for (int e = 0; e < NUM_EXPERTS; ++e) {
    int n = meta[M_COUNTS + e];
    meta[M_OFFSETS + e] = off;
    meta[M_CURSORS + e] = off;
    int tn = (n + 127) >> 7;
    for (int i = 0; i < tn; ++i) {
      meta[M_TILE_E + nt] = e;
      meta[M_TILE_M0 + nt] = off + i * 128;
      meta[M_TILE_ROWS + nt] = min(128, n - i * 128);
      ++nt;
    }
    off += n;
  }
  meta[M_OFFSETS + NUM_EXPERTS] = off;
  meta[M_NUMTILES] = nt;
}

// ---------------- scatter pairs into expert-sorted order ----------------
__global__ __launch_bounds__(256) void k_scatter(
    const int* __restrict__ topk_idx, const float* __restrict__ topk_w,
    int* __restrict__ meta, int* __restrict__ pair_token, float* __restrict__ pair_weight)
{
  int i = blockIdx.x * 256 + threadIdx.x;   // 0..T*8-1
  int e = topk_idx[i];
  int pos = atomicAdd(&meta[M_CURSORS + e], 1);
  pair_token[pos] = i >> 3;
  pair_weight[pos] = topk_w[i];
}

// ---------------- GEMM1: act = silu(x@Wg^T) * (x@Wu^T), gathered rows ----------------
// C tile: 128 pair-rows x 256 cols (128 g + 128 u) -> per-lane silu fuse.
// Grid: 544*4 blocks, XCD-swizzled so a tile's 4 n-blocks share an XCD (x-slab L2 reuse).
// LDS: As[128][64], Bs[256][64] bf16, 16B-chunk XOR swizzle (chunk c of row r at c^(r&7)).
__global__ __launch_bounds__(256, 2) void k_gemm1(
    const bf16_t* __restrict__ x, const bf16_t* __restrict__ w13,
    const int* __restrict__ meta, const int* __restrict__ pair_token,
    bf16_t* __restrict__ act)
{
  int bid = blockIdx.x;
  int xcd = bid & 7, r2 = bid >> 3;
  int nb = r2 & 3, tile = xcd + 8 * (r2 >> 2);
  if (tile >= meta[M_NUMTILES]) return;
  int e    = meta[M_TILE_E + tile];
  int m0   = meta[M_TILE_M0 + tile];
  int rows = meta[M_TILE_ROWS + tile];
  int n0g  = nb * 128;

  __shared__ __align__(16) char smem[49152];
  char* As = smem;           // [128][64] bf16 swizzled
  char* Bs = smem + 16384;   // [256][64]

  int tid = threadIdx.x;
  int lane = tid & 63, w = tid >> 6;
  int cd = lane & 7;                 // chunk this lane deposits (dest = base + lane*16)
  int lrow = w * 8 + (lane >> 3);    // + i*32 -> row

  const bf16_t* a_src[4];
  const bf16_t* b_src[8];
#pragma unroll
  for (int i = 0; i < 4; ++i) {
    int r = i * 32 + lrow;
    int rr = (r < rows) ? r : 0;               // clamp ragged rows to a valid token
    int tok = pair_token[m0 + rr];
    int cg = cd ^ (r & 7);                     // source chunk for swizzled store
    a_src[i] = x + (size_t)tok * HIDDEN + cg * 8;
  }
#pragma unroll
  for (int i = 0; i < 8; ++i) {
    int r = i * 32 + lrow;                     // 0..255
    int cg = cd ^ (r & 7);
    int gr = (r < 128) ? (n0g + r) : (512 + n0g + (r - 128));
    b_src[i] = w13 + (size_t)e * (2 * INTER) * HIDDEN + (size_t)gr * HIDDEN + cg * 8;
  }
  unsigned lds_off = w * 1024 + lane * 16;     // wave-contiguous (global_load_lds semantics)

  f32x4 acc[2][16] = {};
  int q = lane >> 4, cl = lane & 15;
  int arow0 = (w * 32 + cl) * 128;
  int arow1 = (w * 32 + 16 + cl) * 128;

  for (int k0 = 0; k0 < HIDDEN; k0 += 64) {
#pragma unroll
    for (int i = 0; i < 4; ++i) gld16(As + i * 4096 + lds_off, a_src[i] + k0);
#pragma unroll
    for (int i = 0; i < 8; ++i) gld16(Bs + i * 4096 + lds_off, b_src[i] + k0);
    __syncthreads();
#pragma unroll
    for (int ks = 0; ks < 2; ++ks) {
      int csw = ((ks * 4 + q) ^ (lane & 7)) * 16;   // un-swizzle: frag rows have row&7 == lane&7
      bf16x8 a0 = *(const bf16x8*)(As + arow0 + csw);
      bf16x8 a1 = *(const bf16x8*)(As + arow1 + csw);
#pragma unroll
      for (int in = 0; in < 16; ++in) {
        bf16x8 b = *(const bf16x8*)(Bs + (in * 16 + cl) * 128 + csw);
        acc[0][in] = __builtin_amdgcn_mfma_f32_16x16x32_bf16(a0, b, acc[0][in], 0, 0, 0);
        acc[1][in] = __builtin_amdgcn_mfma_f32_16x16x32_bf16(a1, b, acc[1][in], 0, 0, 0);
      }
    }
    __syncthreads();
  }

  // epilogue: act = silu(g)*u ; g = acc[.][0..7], u = acc[.][8..15] -> same lane, per-lane math
#pragma unroll
  for (int im = 0; im < 2; ++im) {
#pragma unroll
    for (int reg = 0; reg < 4; ++reg) {
      int row = w * 32 + im * 16 + q * 4 + reg;   // C/D: row=(lane>>4)*4+reg, col=lane&15
      if (row < rows) {
        bf16_t* obase = act + (size_t)(m0 + row) * INTER + n0g + cl;
#pragma unroll
        for (int in = 0; in < 8; ++in) {
          float g = acc[im][in][reg];
          float u = acc[im][in + 8][reg];
          float a = (g / (1.f + __expf(-g))) * u;
          obase[in * 16] = (bf16_t)a;
        }
      }
    }
  }
}

// ---------------- GEMM2: out += pw * (act @ w2^T), atomic fp32 accumulate ----------------
// C tile: 128 pair-rows x 256 out-cols; grid 544*6, XCD-swizzled (act slab L2 reuse).
__global__ __launch_bounds__(256, 2) void k_gemm2(
    const bf16_t* __restrict__ act, const bf16_t* __restrict__ w2,
    const int* __restrict__ meta, const int* __restrict__ pair_token,
    const float* __restrict__ pair_weight, float* __restrict__ out)
{
  int bid = blockIdx.x;
  int xcd = bid & 7, r2 = bid >> 3;
  int nb = r2 % 6, tile = xcd + 8 * (r2 / 6);
  if (tile >= meta[M_NUMTILES]) return;
  int e    = meta[M_TILE_E + tile];
  int m0   = meta[M_TILE_M0 + tile];
  int rows = meta[M_TILE_ROWS + tile];
  int n0   = nb * 256;

  __shared__ __align__(16) char smem[49152];
  char* As = smem;           // [128][64]
  char* Bs = smem + 16384;   // [256][64]

  int tid = threadIdx.x;
  int lane = tid & 63, w = tid >> 6;
  int cd = lane & 7;
  int lrow = w * 8 + (lane >> 3);

  const bf16_t* a_src[4];
  const bf16_t* b_src[8];
#pragma unroll
  for (int i = 0; i < 4; ++i) {
    int r = i * 32 + lrow;
    int rr = (r < rows) ? r : 0;
    int cg = cd ^ (r & 7);
    a_src[i] = act + (size_t)(m0 + rr) * INTER + cg * 8;
  }
#pragma unroll
  for (int i = 0; i < 8; ++i) {
    int r = i * 32 + lrow;
    int cg = cd ^ (r & 7);
    b_src[i] = w2 + (size_t)e * HIDDEN * INTER + (size_t)(n0 + r) * INTER + cg * 8;
  }
  unsigned lds_off = w * 1024 + lane * 16;

  f32x4 acc[2][16] = {};
  int q = lane >> 4, cl = lane & 15;
  int arow0 = (w * 32 + cl) * 128;
  int arow1 = (w * 32 + 16 + cl) * 128;

  for (int k0 = 0; k0 < INTER; k0 += 64) {
#pragma unroll
    for (int i = 0; i < 4; ++i) gld16(As + i * 4096 + lds_off, a_src[i] + k0);
#pragma unroll
    for (int i = 0; i < 8; ++i) gld16(Bs + i * 4096 + lds_off, b_src[i] + k0);
    __syncthreads();
#pragma unroll
    for (int ks = 0; ks < 2; ++ks) {
      int csw = ((ks * 4 + q) ^ (lane & 7)) * 16;
      bf16x8 a0 = *(const bf16x8*)(As + arow0 + csw);
      bf16x8 a1 = *(const bf16x8*)(As + arow1 + csw);
#pragma unroll
      for (int in = 0; in < 16; ++in) {
        bf16x8 b = *(const bf16x8*)(Bs + (in * 16 + cl) * 128 + csw);
        acc[0][in] = __builtin_amdgcn_mfma_f32_16x16x32_bf16(a0, b, acc[0][in], 0, 0, 0);
        acc[1][in] = __builtin_amdgcn_mfma_f32_16x16x32_bf16(a1, b, acc[1][in], 0, 0, 0);
      }
    }
    __syncthreads();
  }

#pragma unroll
  for (int im = 0; im < 2; ++im) {
#pragma unroll
    for (int reg = 0; reg < 4; ++reg) {
      int row = w * 32 + im * 16 + q * 4 + reg;
      if (row < rows) {
        int p = m0 + row;
        int tok = pair_token[p];
        float pw = pair_weight[p];
        float* obase = out + (size_t)tok * HIDDEN + n0 + cl;
#pragma unroll
        for (int in = 0; in < 16; ++in)
          unsafeAtomicAdd(obase + in * 16, acc[im][in][reg] * pw);
      }
    }
  }
}

extern "C" void kernel_launch(void* const* d_in, const int* in_sizes, int n_in,
                              void* d_out, int out_size, void* d_ws, size_t ws_size,
                              hipStream_t stream)
{
  const float* x   = (const float*)d_in[0];
  const float* gw  = (const float*)d_in[1];
  const float* w13 = (const float*)d_in[2];
  const float* w2  = (const float*)d_in[3];
  float* out = (float*)d_out;

  const int T = in_sizes[0] / HIDDEN;   // 8192
  const int P = T * TOP_K;              // 65536
  const size_t NX   = (size_t)T * HIDDEN;
  const size_t NW13 = (size_t)NUM_EXPERTS * 2 * INTER * HIDDEN;
  const size_t NW2  = (size_t)NUM_EXPERTS * HIDDEN * INTER;

  char* ws = (char*)d_ws;
  int*    meta        = (int*)ws;                              // 16 KB
  int*    topk_idx    = (int*)(ws + META_BYTES);               // P ints
  float*  topk_w      = (float*)(ws + META_BYTES + (size_t)P * 4);
  int*    pair_token  = (int*)(ws + META_BYTES + (size_t)P * 8);
  float*  pair_weight = (float*)(ws + META_BYTES + (size_t)P * 12);
  float*  gwT4        = (float*)(ws + (1536u << 10));          // 192 KB
  size_t off = 2u << 20;
  bf16_t* x16    = (bf16_t*)(ws + off); off += NX * 2;         // 25.2 MB
  bf16_t* w13_16 = (bf16_t*)(ws + off); off += NW13 * 2;       // 100.7 MB
  bf16_t* w2_16  = (bf16_t*)(ws + off); off += NW2 * 2;        // 50.3 MB
  bf16_t* act    = (bf16_t*)(ws + off);                        // P*512*2 = 67.1 MB

  hipMemsetAsync(meta, 0, 32 * sizeof(int), stream);
  hipMemsetAsync(out, 0, (size_t)out_size * sizeof(float), stream);

  k_tgw<<<(HIDDEN * NUM_EXPERTS) / 256, 256, 0, stream>>>(gw, gwT4);
  k_cvt<<<NW13 / 1024, 256, 0, stream>>>(w13, w13_16);
  k_cvt<<<NW2 / 1024, 256, 0, stream>>>(w2, w2_16);

  k_router<<<T, 64, 0, stream>>>(x, gwT4, meta, topk_idx, topk_w, x16);
  k_scan<<<1, 64, 0, stream>>>(meta);
  k_scatter<<<P / 256, 256, 0, stream>>>(topk_idx, topk_w, meta, pair_token, pair_weight);

  // 544 = 68*8 max ragged tiles; XCD-swizzled 1D grids
  k_gemm1<<<544 * 4, 256, 0, stream>>>(x16, w13_16, meta, pair_token, act);
  k_gemm2<<<544 * 6, 256, 0, stream>>>(act, w2_16, meta, pair_token, pair_weight, out);
}